// Round 13
// baseline (493.550 us; speedup 1.0000x reference)
//
#include <hip/hip_runtime.h>
#include <hip/hip_bf16.h>
#include <stdint.h>

// x: (4,4096,4096) f32 ; W_kv/W_gate: (1024,4096) f32 ; ape: (4,1024)
// norm_w: (512,) ; freqs_cis: (1024,32,2) ; out: (4,1024,512) f32
#define M_ROWS 16384
#define N_COLS 2048
#define K_DIM  4096
#define NEGV   -1e30f

typedef __bf16 bfv8 __attribute__((ext_vector_type(8)));
typedef float  f32x4 __attribute__((ext_vector_type(4)));
typedef unsigned short u16;

static __device__ __forceinline__ u16 f32_to_bf16_rne(float f) {
  union { float f; unsigned int u; } v; v.f = f;
  unsigned int u = v.u;
  u += 0x7fffu + ((u >> 16) & 1u);
  return (u16)(u >> 16);
}

static __device__ __forceinline__ float b2f(u16 b) {
  union { unsigned int u; float f; } v; v.u = ((unsigned int)b) << 16;
  return v.f;
}

// ---------- fused conversion: [x ; W_kv ; W_gate] f32 -> bf16, contiguous dst ----------
__global__ __launch_bounds__(256) void k_cvt(const float* __restrict__ x,
                                             const float* __restrict__ wkv,
                                             const float* __restrict__ wg,
                                             u16* __restrict__ dst) {
  long i = (long)blockIdx.x * blockDim.x + threadIdx.x;
  long base = i * 8;                      // < 75497472 total elems
  const float* src;
  if (base < 67108864L) {
    src = x + base;
  } else {
    long wi = base - 67108864L;
    src = (wi < 4194304L) ? (wkv + wi) : (wg + (wi - 4194304L));
  }
  float4 a = *(const float4*)(src);
  float4 b = *(const float4*)(src + 4);
  union { u16 s[8]; uint4 v; } o;
  o.s[0] = f32_to_bf16_rne(a.x); o.s[1] = f32_to_bf16_rne(a.y);
  o.s[2] = f32_to_bf16_rne(a.z); o.s[3] = f32_to_bf16_rne(a.w);
  o.s[4] = f32_to_bf16_rne(b.x); o.s[5] = f32_to_bf16_rne(b.y);
  o.s[6] = f32_to_bf16_rne(b.z); o.s[7] = f32_to_bf16_rne(b.w);
  *(uint4*)(dst + base) = o.v;
}

// ---------- GEMM: 256x256 tile, BK=64, 8 waves; A in LDS (64KB, swizzled),
// ---------- B fragments direct global->reg (L2-hot weights), 2 blocks/CU ----------
// A: 16384x4096 bf16, B: 2048x4096 bf16, C = A.B^T (bf16)
// LDS (u16 idx): A[buf][kk] at buf*16384 + kk*8192. 64 KiB total -> 2 blocks/CU.
// Line l (128B) = rows {2l,2l+1}; granule G' = (((row&1)<<2)|g) ^ (l&7).
// B frag (ni,kk): lane(fr,fq) reads B[gn0+wc*64+ni*16+fr][kt+kk*32+fq*8 ..+8]
//   = 16B, naturally coalesced (16 rows x 64B lines). u-set = kk0 (loaded ph3 of
//   prev tile), v-set = kk1 (loaded ph1). Compiler emits precise vmcnt for reg deps.
// Manual VM6: ph2 retires A(P,1) [needed ph3]; ph4 retires A(Q,0) [needed next ph1].
// WAR: STAGE into (Q,kk) is >=2 barriers after last reads of that region. [derived r12]
#define GLD16(g, l) __builtin_amdgcn_global_load_lds( \
    (const __attribute__((address_space(1))) unsigned int*)(g), \
    (__attribute__((address_space(3))) unsigned int*)(l), 16, 0, 0)

#define SB0 __builtin_amdgcn_sched_barrier(0)
#define BAR __builtin_amdgcn_s_barrier()
#define VM6 asm volatile("s_waitcnt vmcnt(6)" ::: "memory")
#define VM0 asm volatile("s_waitcnt vmcnt(0)" ::: "memory")

__global__ __launch_bounds__(512, 2) void k_gemm(const u16* __restrict__ A,
                                                 const u16* __restrict__ B,
                                                 u16* __restrict__ C) {
  __shared__ u16 lds[32768]; // 64 KiB (A only)

  const int tid  = threadIdx.x;
  const int wid  = tid >> 6;
  const int lane = tid & 63;
  const int wr = wid >> 2, wc = wid & 3;   // 2x4 wave grid; wave tile 128x64
  const int fr = lane & 15, fq = lane >> 4;

  // XCD-aware swizzle (r6-proven): grid 512 = 64 bm x 8 bn
  int o = blockIdx.x;
  int swz = (o & 7) * 64 + (o >> 3);
  const int bm = swz >> 3, bn = swz & 7;
  const int gm0 = bm << 8, gn0 = bn << 8;

  // A fragment ds_read offsets (u16 units) within a kk-half region
  int aoff[8];
#pragma unroll
  for (int mi = 0; mi < 8; ++mi) {
    int row = (wr << 7) + (mi << 4) + fr;
    int Gp = (((row & 1) << 2) | fq) ^ ((row >> 1) & 7);
    aoff[mi] = (row >> 1) * 64 + Gp * 8;
  }

  // B fragment global base pointers (per ni): col*4096 + fq*8
  const u16* pBf0 = B + ((size_t)(gn0 + (wc << 6) +  0 + fr) << 12) + (fq << 3);
  const u16* pBf1 = B + ((size_t)(gn0 + (wc << 6) + 16 + fr) << 12) + (fq << 3);
  const u16* pBf2 = B + ((size_t)(gn0 + (wc << 6) + 32 + fr) << 12) + (fq << 3);
  const u16* pBf3 = B + ((size_t)(gn0 + (wc << 6) + 48 + fr) << 12) + (fq << 3);

  // A staging: slot s = j*512+tid covers physical 16B slot; inverse-swizzled src
  const int s0 = tid, s1 = 512 + tid;
  const int l0 = s0 >> 3, G0 = (s0 & 7) ^ (l0 & 7);
  const int r0 = 2 * l0 + (G0 >> 2), g0 = (G0 & 3) << 3;
  const int l1 = s1 >> 3, G1 = (s1 & 7) ^ (l1 & 7);
  const int r1 = 2 * l1 + (G1 >> 2), g1 = (G1 & 3) << 3;
  const u16* pA0 = A + ((size_t)(gm0 + r0) << 12) + g0;
  const u16* pA1 = A + ((size_t)(gm0 + r1) << 12) + g1;
  const int du0 = wid << 9;           // wave-uniform LDS dest (u16)
  const int du1 = 4096 + (wid << 9);

#define STAGE_A(Q, KK, KTN) do { \
  GLD16(pA0 + (KTN) + (KK) * 32, &lds[(Q) * 16384 + (KK) * 8192 + du0]); \
  GLD16(pA1 + (KTN) + (KK) * 32, &lds[(Q) * 16384 + (KK) * 8192 + du1]); } while (0)
#define LDA(P, KK, MI) (*(const bfv8*)&lds[(P) * 16384 + (KK) * 8192 + aoff[MI]])
#define BLOADU(KT) do { \
  u0 = *(const bfv8*)(pBf0 + (KT)); u1 = *(const bfv8*)(pBf1 + (KT)); \
  u2 = *(const bfv8*)(pBf2 + (KT)); u3 = *(const bfv8*)(pBf3 + (KT)); } while (0)
#define BLOADV(KT) do { \
  v0 = *(const bfv8*)(pBf0 + (KT)); v1 = *(const bfv8*)(pBf1 + (KT)); \
  v2 = *(const bfv8*)(pBf2 + (KT)); v3 = *(const bfv8*)(pBf3 + (KT)); } while (0)
#define MF(AV, BV, MI, NI) acc[MI][NI] = __builtin_amdgcn_mfma_f32_16x16x32_bf16(AV, BV, acc[MI][NI], 0, 0, 0)
#define MF4U(AV, MI) do { MF(AV, u0, MI, 0); MF(AV, u1, MI, 1); MF(AV, u2, MI, 2); MF(AV, u3, MI, 3); } while (0)
#define MF4V(AV, MI) do { MF(AV, v0, MI, 0); MF(AV, v1, MI, 1); MF(AV, v2, MI, 2); MF(AV, v3, MI, 3); } while (0)

  f32x4 acc[8][4];
#pragma unroll
  for (int i = 0; i < 8; ++i)
#pragma unroll
    for (int j = 0; j < 4; ++j) acc[i][j] = (f32x4){0.f, 0.f, 0.f, 0.f};

  bfv8 a0, a1, a2, a3, a4, a5, a6, a7;
  bfv8 u0, u1, u2, u3, v0, v1, v2, v3;

  // prologue: A(tile0, both kk) -> LDS buf0; B u-set (tile0 kk0) -> regs
  BLOADU(0);
  STAGE_A(0, 0, 0); STAGE_A(0, 1, 0);
  SB0; VM0; BAR; SB0;

  // per K-tile (read buf P, stage next-tile A into Q; KT1 = this tile's k, KT2 = next's):
  // ph1: rd A0-3 (P,0); BLOADV(KT1+32); STAGE_A(Q,0,KT2) | bar | 16 mfma (a x u)
  // ph2: rd A4-7 (P,0)                                   | vm6 bar | 16 mfma (a x u)   vm6 -> A(P,1)
  // ph3: rd A0-3 (P,1); BLOADU(KT2);    STAGE_A(Q,1,KT2) | bar | 16 mfma (a x v)
  // ph4: rd A4-7 (P,1)                                   | vm6 bar | 16 mfma (a x v)   vm6 -> A(Q,0)
#define KTILE(P, Q, KT1, KT2) do { \
  a0 = LDA(P, 0, 0); a1 = LDA(P, 0, 1); a2 = LDA(P, 0, 2); a3 = LDA(P, 0, 3); \
  BLOADV((KT1) + 32); \
  STAGE_A(Q, 0, KT2); \
  SB0; BAR; SB0; \
  __builtin_amdgcn_s_setprio(1); \
  MF4U(a0, 0); MF4U(a1, 1); MF4U(a2, 2); MF4U(a3, 3); \
  __builtin_amdgcn_s_setprio(0); SB0; \
  a4 = LDA(P, 0, 4); a5 = LDA(P, 0, 5); a6 = LDA(P, 0, 6); a7 = LDA(P, 0, 7); \
  SB0; VM6; BAR; SB0; \
  __builtin_amdgcn_s_setprio(1); \
  MF4U(a4, 4); MF4U(a5, 5); MF4U(a6, 6); MF4U(a7, 7); \
  __builtin_amdgcn_s_setprio(0); SB0; \
  a0 = LDA(P, 1, 0); a1 = LDA(P, 1, 1); a2 = LDA(P, 1, 2); a3 = LDA(P, 1, 3); \
  BLOADU(KT2); \
  STAGE_A(Q, 1, KT2); \
  SB0; BAR; SB0; \
  __builtin_amdgcn_s_setprio(1); \
  MF4V(a0, 0); MF4V(a1, 1); MF4V(a2, 2); MF4V(a3, 3); \
  __builtin_amdgcn_s_setprio(0); SB0; \
  a4 = LDA(P, 1, 4); a5 = LDA(P, 1, 5); a6 = LDA(P, 1, 6); a7 = LDA(P, 1, 7); \
  SB0; VM6; BAR; SB0; \
  __builtin_amdgcn_s_setprio(1); \
  MF4V(a4, 4); MF4V(a5, 5); MF4V(a6, 6); MF4V(a7, 7); \
  __builtin_amdgcn_s_setprio(0); SB0; \
} while (0)

  for (int i = 0; i < 32; ++i) {
    const int ktA = (2 * i) << 6;
    const int ktB = (2 * i + 1) << 6;
    const int ktC = (i == 31) ? 0 : (2 * i + 2) << 6; // dummy on last iter (never used as data)
    KTILE(0, 1, ktA, ktB);
    KTILE(1, 0, ktB, ktC);
  }

  // epilogue: C/D layout col = lane&15, row = (lane>>4)*4 + reg ; store bf16
#pragma unroll
  for (int mi = 0; mi < 8; ++mi) {
    int row = gm0 + (wr << 7) + (mi << 4) + (fq << 2);
#pragma unroll
    for (int ni = 0; ni < 4; ++ni) {
      int col = gn0 + (wc << 6) + (ni << 4) + fr;
#pragma unroll
      for (int j = 0; j < 4; ++j)
        C[(size_t)(row + j) * N_COLS + col] = f32_to_bf16_rne(acc[mi][ni][j]);
    }
  }
#undef KTILE
#undef STAGE_A
#undef LDA
#undef BLOADU
#undef BLOADV
#undef MF
#undef MF4U
#undef MF4V
}

// ---------- pool + RMSNorm + RoPE + FWHT (bf16 input) ----------
__global__ __launch_bounds__(256) void k_pool(const u16* __restrict__ kvsc,  // 16384x2048 bf16
                                              const float* __restrict__ ape,
                                              const float* __restrict__ norm_w,
                                              const float* __restrict__ freqs,
                                              float* __restrict__ out) {
  __shared__ float sm[512];
  __shared__ float red[8];
  const int tid = threadIdx.x;
  const int bid = blockIdx.x;
  const int b = bid >> 10, ib = bid & 1023;

  float ss = 0.f;
#pragma unroll
  for (int cc = 0; cc < 2; ++cc) {
    int c = tid + (cc << 8);
    float kvv[8], scv[8];
    if (ib > 0) {
      size_t mb = ((size_t)b * 4096 + (size_t)(ib - 1) * 4);
#pragma unroll
      for (int p = 0; p < 4; ++p) {
        size_t ro = (mb + p) * N_COLS;
        kvv[p] = b2f(kvsc[ro + c]) + ape[p * 1024 + c];
        scv[p] = b2f(kvsc[ro + 1024 + c]);
      }
    } else {
#pragma unroll
      for (int p = 0; p < 4; ++p) { kvv[p] = 0.f; scv[p] = NEGV; }
    }
    size_t mb2 = ((size_t)b * 4096 + (size_t)ib * 4);
#pragma unroll
    for (int r = 0; r < 4; ++r) {
      size_t ro = (mb2 + r) * N_COLS;
      kvv[4 + r] = b2f(kvsc[ro + 512 + c]) + ape[r * 1024 + 512 + c];
      scv[4 + r] = b2f(kvsc[ro + 1024 + 512 + c]);
    }
    float mx = scv[0];
#pragma unroll
    for (int p = 1; p < 8; ++p) mx = fmaxf(mx, scv[p]);
    float se = 0.f, ac = 0.f;
#pragma unroll
    for (int p = 0; p < 8; ++p) {
      float e = __expf(scv[p] - mx);
      se += e; ac += e * kvv[p];
    }
    float pooled = ac / se;
    sm[c] = pooled;
    ss += pooled * pooled;
  }
#pragma unroll
  for (int m = 1; m < 64; m <<= 1) ss += __shfl_xor(ss, m, 64);
  if ((tid & 63) == 0) red[tid >> 6] = ss;
  __syncthreads();
  float sumsq = red[0] + red[1] + red[2] + red[3];
  float scale = rsqrtf(sumsq * (1.f / 512.f) + 1e-6f);
  sm[tid]       = sm[tid]       * scale * norm_w[tid];
  sm[tid + 256] = sm[tid + 256] * scale * norm_w[tid + 256];
  __syncthreads();
  if (tid < 32) {
    int j = tid;
    float xr = sm[448 + 2 * j], xi = sm[449 + 2 * j];
    float fr = freqs[((size_t)ib * 32 + j) * 2];
    float fi = freqs[((size_t)ib * 32 + j) * 2 + 1];
    sm[448 + 2 * j] = xr * fr - xi * fi;
    sm[449 + 2 * j] = xr * fi + xi * fr;
  }
  __syncthreads();
#pragma unroll
  for (int k = 0; k < 9; ++k) {
    int low = tid & ((1 << k) - 1);
    int i0 = ((tid >> k) << (k + 1)) | low;
    int i1 = i0 | (1 << k);
    float a = sm[i0], bb = sm[i1];
    sm[i0] = a + bb; sm[i1] = a - bb;
    __syncthreads();
  }
  const float OSC = 0.044194173824159216f; // 1/sqrt(512)
  size_t ob = (size_t)bid * 512;
  out[ob + tid]       = sm[tid] * OSC;
  out[ob + tid + 256] = sm[tid + 256] * OSC;
}

extern "C" void kernel_launch(void* const* d_in, const int* in_sizes, int n_in,
                              void* d_out, int out_size, void* d_ws, size_t ws_size,
                              hipStream_t stream) {
  const float* x      = (const float*)d_in[0];
  const float* W_kv   = (const float*)d_in[1];
  const float* W_gate = (const float*)d_in[2];
  const float* ape    = (const float*)d_in[3];
  const float* norm_w = (const float*)d_in[4];
  const float* freqs  = (const float*)d_in[5];
  float* out = (float*)d_out;

  char* ws = (char*)d_ws;
  u16* xb   = (u16*)ws;                                  // 134217728 B (x bf16)
  u16* wb   = (u16*)(ws + 134217728L);                   // 16777216 B  (W bf16, contiguous after xb)
  u16* kvsc = (u16*)(ws + 134217728L + 16777216L);       // 67108864 B  (bf16 C)

  hipLaunchKernelGGL(k_cvt, dim3(36864), dim3(256), 0, stream, x, W_kv, W_gate, xb);
  hipLaunchKernelGGL(k_gemm, dim3(512), dim3(512), 0, stream, xb, wb, kvsc);
  hipLaunchKernelGGL(k_pool, dim3(4096), dim3(256), 0, stream, kvsc, ape, norm_w, freqs, out);
}

// Round 14
// 311.863 us; speedup vs baseline: 1.5826x; 1.5826x over previous
//
#include <hip/hip_runtime.h>
#include <hip/hip_bf16.h>
#include <stdint.h>

// x: (4,4096,4096) f32 ; W_kv/W_gate: (1024,4096) f32 ; ape: (4,1024)
// norm_w: (512,) ; freqs_cis: (1024,32,2) ; out: (4,1024,512) f32
#define M_ROWS 16384
#define N_COLS 2048
#define K_DIM  4096
#define NEGV   -1e30f

typedef __bf16 bfv8 __attribute__((ext_vector_type(8)));
typedef float  f32x4 __attribute__((ext_vector_type(4)));
typedef unsigned short u16;

static __device__ __forceinline__ u16 f32_to_bf16_rne(float f) {
  union { float f; unsigned int u; } v; v.f = f;
  unsigned int u = v.u;
  u += 0x7fffu + ((u >> 16) & 1u);
  return (u16)(u >> 16);
}

static __device__ __forceinline__ float b2f(u16 b) {
  union { unsigned int u; float f; } v; v.u = ((unsigned int)b) << 16;
  return v.f;
}

// ---------- fused conversion: [x ; W_kv ; W_gate] f32 -> bf16, contiguous dst ----------
__global__ __launch_bounds__(256) void k_cvt(const float* __restrict__ x,
                                             const float* __restrict__ wkv,
                                             const float* __restrict__ wg,
                                             u16* __restrict__ dst) {
  long i = (long)blockIdx.x * blockDim.x + threadIdx.x;
  long base = i * 8;                      // < 75497472 total elems
  const float* src;
  if (base < 67108864L) {
    src = x + base;
  } else {
    long wi = base - 67108864L;
    src = (wi < 4194304L) ? (wkv + wi) : (wg + (wi - 4194304L));
  }
  float4 a = *(const float4*)(src);
  float4 b = *(const float4*)(src + 4);
  union { u16 s[8]; uint4 v; } o;
  o.s[0] = f32_to_bf16_rne(a.x); o.s[1] = f32_to_bf16_rne(a.y);
  o.s[2] = f32_to_bf16_rne(a.z); o.s[3] = f32_to_bf16_rne(a.w);
  o.s[4] = f32_to_bf16_rne(b.x); o.s[5] = f32_to_bf16_rne(b.y);
  o.s[6] = f32_to_bf16_rne(b.z); o.s[7] = f32_to_bf16_rne(b.w);
  *(uint4*)(dst + base) = o.v;
}

// ---------- GEMM: 256x256 tile, BK=64, 8 waves, 8-phase pipelined (champion, exact) ----------
// A: 16384x4096 bf16, B: 2048x4096 bf16, C = A.B^T (bf16)
// LDS (u16 idx): A[buf][kk] at buf*16384 + kk*8192 ; B at +32768.
// K-half tile = 256 rows x 32 k. Storage: line l (128B) holds rows {2l,2l+1},
// 16B-granule G' = (((row&1)<<2)|g) ^ (l&7)  (XOR involution, bank-spread).
// Measured champion: gemm ~231us, MfmaUtil 55%, 0 bank conflicts, FETCH 200MB.
// Seven structural deviations tested (r7-r13) all regressed; do not modify.
#define GLD16(g, l) __builtin_amdgcn_global_load_lds( \
    (const __attribute__((address_space(1))) unsigned int*)(g), \
    (__attribute__((address_space(3))) unsigned int*)(l), 16, 0, 0)

#define SB0 __builtin_amdgcn_sched_barrier(0)
#define BAR __builtin_amdgcn_s_barrier()
#define VM4 asm volatile("s_waitcnt vmcnt(4)" ::: "memory")

__global__ __launch_bounds__(512, 2) void k_gemm(const u16* __restrict__ A,
                                                 const u16* __restrict__ B,
                                                 u16* __restrict__ C) {
  __shared__ u16 lds[65536]; // 128 KiB

  const int tid  = threadIdx.x;
  const int wid  = tid >> 6;
  const int lane = tid & 63;
  const int wr = wid >> 2, wc = wid & 3;   // 2x4 wave grid; wave tile 128x64
  const int fr = lane & 15, fq = lane >> 4;

  // XCD-aware swizzle: grid 512 = 64 bm x 8 bn, nwg%8==0
  int o = blockIdx.x;
  int swz = (o & 7) * 64 + (o >> 3);
  const int bm = swz >> 3, bn = swz & 7;
  const int gm0 = bm << 8, gn0 = bn << 8;

  // fragment ds_read offsets (u16 units) within a kk-half region
  int aoff[8], boff[4];
#pragma unroll
  for (int mi = 0; mi < 8; ++mi) {
    int row = (wr << 7) + (mi << 4) + fr;
    int Gp = (((row & 1) << 2) | fq) ^ ((row >> 1) & 7);
    aoff[mi] = (row >> 1) * 64 + Gp * 8;
  }
#pragma unroll
  for (int ni = 0; ni < 4; ++ni) {
    int row = (wc << 6) + (ni << 4) + fr;
    int Gp = (((row & 1) << 2) | fq) ^ ((row >> 1) & 7);
    boff[ni] = (row >> 1) * 64 + Gp * 8;
  }

  // staging: slot s = j*512+tid covers physical 16B slot; inverse-swizzled src
  const int s0 = tid, s1 = 512 + tid;
  const int l0 = s0 >> 3, G0 = (s0 & 7) ^ (l0 & 7);
  const int r0 = 2 * l0 + (G0 >> 2), g0 = (G0 & 3) << 3;
  const int l1 = s1 >> 3, G1 = (s1 & 7) ^ (l1 & 7);
  const int r1 = 2 * l1 + (G1 >> 2), g1 = (G1 & 3) << 3;
  const u16* pA0 = A + ((size_t)(gm0 + r0) << 12) + g0;
  const u16* pA1 = A + ((size_t)(gm0 + r1) << 12) + g1;
  const u16* pB0 = B + ((size_t)(gn0 + r0) << 12) + g0;
  const u16* pB1 = B + ((size_t)(gn0 + r1) << 12) + g1;
  const int du0 = wid << 9;           // wave-uniform LDS dest (u16)
  const int du1 = 4096 + (wid << 9);

#define STAGE_A(Q, KK, KTN) do { \
  GLD16(pA0 + (KTN) + (KK) * 32, &lds[(Q) * 16384 + (KK) * 8192 + du0]); \
  GLD16(pA1 + (KTN) + (KK) * 32, &lds[(Q) * 16384 + (KK) * 8192 + du1]); } while (0)
#define STAGE_B(Q, KK, KTN) do { \
  GLD16(pB0 + (KTN) + (KK) * 32, &lds[32768 + (Q) * 16384 + (KK) * 8192 + du0]); \
  GLD16(pB1 + (KTN) + (KK) * 32, &lds[32768 + (Q) * 16384 + (KK) * 8192 + du1]); } while (0)
#define LDA(P, KK, MI) (*(const bfv8*)&lds[(P) * 16384 + (KK) * 8192 + aoff[MI]])
#define LDB(P, KK, NI) (*(const bfv8*)&lds[32768 + (P) * 16384 + (KK) * 8192 + boff[NI]])
#define MF(AV, BV, MI, NI) acc[MI][NI] = __builtin_amdgcn_mfma_f32_16x16x32_bf16(AV, BV, acc[MI][NI], 0, 0, 0)
#define MF4(AV, MI) do { MF(AV, b0, MI, 0); MF(AV, b1, MI, 1); MF(AV, b2, MI, 2); MF(AV, b3, MI, 3); } while (0)

  f32x4 acc[8][4];
#pragma unroll
  for (int i = 0; i < 8; ++i)
#pragma unroll
    for (int j = 0; j < 4; ++j) acc[i][j] = (f32x4){0.f, 0.f, 0.f, 0.f};

  // prologue: stage K-tile 0 (buf 0): A-kk0, B-kk0, A-kk1, B-kk1
  STAGE_A(0, 0, 0); STAGE_B(0, 0, 0); STAGE_A(0, 1, 0); STAGE_B(0, 1, 0);
  SB0; VM4; BAR; SB0;

  bfv8 a0, a1, a2, a3, a4, a5, a6, a7, b0, b1, b2, b3;

  // per K-tile (read buf P, stage K-tile'(KTN) into buf Q):
  // ph1: rd A0-3/B0-3 kk0, stage A-kk0' | bar | 16 mfma
  // ph2: rd A4-7 kk0,      stage B-kk0' | vmcnt(4) bar | 16 mfma   (kk1 of P landed)
  // ph3: rd A0-3/B0-3 kk1, stage A-kk1' | bar | 16 mfma
  // ph4: rd A4-7 kk1,      stage B-kk1' | vmcnt(4) bar | 16 mfma   (kk0 of Q landed)
#define KTILE(P, Q, KTN) do { \
  a0 = LDA(P, 0, 0); a1 = LDA(P, 0, 1); a2 = LDA(P, 0, 2); a3 = LDA(P, 0, 3); \
  b0 = LDB(P, 0, 0); b1 = LDB(P, 0, 1); b2 = LDB(P, 0, 2); b3 = LDB(P, 0, 3); \
  STAGE_A(Q, 0, KTN); \
  SB0; BAR; SB0; \
  __builtin_amdgcn_s_setprio(1); \
  MF4(a0, 0); MF4(a1, 1); MF4(a2, 2); MF4(a3, 3); \
  __builtin_amdgcn_s_setprio(0); SB0; \
  a4 = LDA(P, 0, 4); a5 = LDA(P, 0, 5); a6 = LDA(P, 0, 6); a7 = LDA(P, 0, 7); \
  STAGE_B(Q, 0, KTN); \
  SB0; VM4; BAR; SB0; \
  __builtin_amdgcn_s_setprio(1); \
  MF4(a4, 4); MF4(a5, 5); MF4(a6, 6); MF4(a7, 7); \
  __builtin_amdgcn_s_setprio(0); SB0; \
  a0 = LDA(P, 1, 0); a1 = LDA(P, 1, 1); a2 = LDA(P, 1, 2); a3 = LDA(P, 1, 3); \
  b0 = LDB(P, 1, 0); b1 = LDB(P, 1, 1); b2 = LDB(P, 1, 2); b3 = LDB(P, 1, 3); \
  STAGE_A(Q, 1, KTN); \
  SB0; BAR; SB0; \
  __builtin_amdgcn_s_setprio(1); \
  MF4(a0, 0); MF4(a1, 1); MF4(a2, 2); MF4(a3, 3); \
  __builtin_amdgcn_s_setprio(0); SB0; \
  a4 = LDA(P, 1, 4); a5 = LDA(P, 1, 5); a6 = LDA(P, 1, 6); a7 = LDA(P, 1, 7); \
  STAGE_B(Q, 1, KTN); \
  SB0; VM4; BAR; SB0; \
  __builtin_amdgcn_s_setprio(1); \
  MF4(a4, 4); MF4(a5, 5); MF4(a6, 6); MF4(a7, 7); \
  __builtin_amdgcn_s_setprio(0); SB0; \
} while (0)

  for (int i = 0; i < 32; ++i) {
    const int kt1 = (2 * i + 1) << 6;
    const int kt2 = (i == 31) ? 0 : (2 * i + 2) << 6; // last iter: dummy (never read)
    KTILE(0, 1, kt1);
    KTILE(1, 0, kt2);
  }

  // epilogue: C/D layout col = lane&15, row = (lane>>4)*4 + reg ; store bf16
#pragma unroll
  for (int mi = 0; mi < 8; ++mi) {
    int row = gm0 + (wr << 7) + (mi << 4) + (fq << 2);
#pragma unroll
    for (int ni = 0; ni < 4; ++ni) {
      int col = gn0 + (wc << 6) + (ni << 4) + fr;
#pragma unroll
      for (int j = 0; j < 4; ++j)
        C[(size_t)(row + j) * N_COLS + col] = f32_to_bf16_rne(acc[mi][ni][j]);
    }
  }
#undef KTILE
#undef STAGE_A
#undef STAGE_B
#undef LDA
#undef LDB
#undef MF
#undef MF4
}

// ---------- pool + RMSNorm + RoPE + FWHT (bf16 input) ----------
__global__ __launch_bounds__(256) void k_pool(const u16* __restrict__ kvsc,  // 16384x2048 bf16
                                              const float* __restrict__ ape,
                                              const float* __restrict__ norm_w,
                                              const float* __restrict__ freqs,
                                              float* __restrict__ out) {
  __shared__ float sm[512];
  __shared__ float red[8];
  const int tid = threadIdx.x;
  const int bid = blockIdx.x;
  const int b = bid >> 10, ib = bid & 1023;

  float ss = 0.f;
#pragma unroll
  for (int cc = 0; cc < 2; ++cc) {
    int c = tid + (cc << 8);
    float kvv[8], scv[8];
    if (ib > 0) {
      size_t mb = ((size_t)b * 4096 + (size_t)(ib - 1) * 4);
#pragma unroll
      for (int p = 0; p < 4; ++p) {
        size_t ro = (mb + p) * N_COLS;
        kvv[p] = b2f(kvsc[ro + c]) + ape[p * 1024 + c];
        scv[p] = b2f(kvsc[ro + 1024 + c]);
      }
    } else {
#pragma unroll
      for (int p = 0; p < 4; ++p) { kvv[p] = 0.f; scv[p] = NEGV; }
    }
    size_t mb2 = ((size_t)b * 4096 + (size_t)ib * 4);
#pragma unroll
    for (int r = 0; r < 4; ++r) {
      size_t ro = (mb2 + r) * N_COLS;
      kvv[4 + r] = b2f(kvsc[ro + 512 + c]) + ape[r * 1024 + 512 + c];
      scv[4 + r] = b2f(kvsc[ro + 1024 + 512 + c]);
    }
    float mx = scv[0];
#pragma unroll
    for (int p = 1; p < 8; ++p) mx = fmaxf(mx, scv[p]);
    float se = 0.f, ac = 0.f;
#pragma unroll
    for (int p = 0; p < 8; ++p) {
      float e = __expf(scv[p] - mx);
      se += e; ac += e * kvv[p];
    }
    float pooled = ac / se;
    sm[c] = pooled;
    ss += pooled * pooled;
  }
#pragma unroll
  for (int m = 1; m < 64; m <<= 1) ss += __shfl_xor(ss, m, 64);
  if ((tid & 63) == 0) red[tid >> 6] = ss;
  __syncthreads();
  float sumsq = red[0] + red[1] + red[2] + red[3];
  float scale = rsqrtf(sumsq * (1.f / 512.f) + 1e-6f);
  sm[tid]       = sm[tid]       * scale * norm_w[tid];
  sm[tid + 256] = sm[tid + 256] * scale * norm_w[tid + 256];
  __syncthreads();
  if (tid < 32) {
    int j = tid;
    float xr = sm[448 + 2 * j], xi = sm[449 + 2 * j];
    float fr = freqs[((size_t)ib * 32 + j) * 2];
    float fi = freqs[((size_t)ib * 32 + j) * 2 + 1];
    sm[448 + 2 * j] = xr * fr - xi * fi;
    sm[449 + 2 * j] = xr * fi + xi * fr;
  }
  __syncthreads();
#pragma unroll
  for (int k = 0; k < 9; ++k) {
    int low = tid & ((1 << k) - 1);
    int i0 = ((tid >> k) << (k + 1)) | low;
    int i1 = i0 | (1 << k);
    float a = sm[i0], bb = sm[i1];
    sm[i0] = a + bb; sm[i1] = a - bb;
    __syncthreads();
  }
  const float OSC = 0.044194173824159216f; // 1/sqrt(512)
  size_t ob = (size_t)bid * 512;
  out[ob + tid]       = sm[tid] * OSC;
  out[ob + tid + 256] = sm[tid + 256] * OSC;
}

extern "C" void kernel_launch(void* const* d_in, const int* in_sizes, int n_in,
                              void* d_out, int out_size, void* d_ws, size_t ws_size,
                              hipStream_t stream) {
  const float* x      = (const float*)d_in[0];
  const float* W_kv   = (const float*)d_in[1];
  const float* W_gate = (const float*)d_in[2];
  const float* ape    = (const float*)d_in[3];
  const float* norm_w = (const float*)d_in[4];
  const float* freqs  = (const float*)d_in[5];
  float* out = (float*)d_out;

  char* ws = (char*)d_ws;
  u16* xb   = (u16*)ws;                                  // 134217728 B (x bf16)
  u16* wb   = (u16*)(ws + 134217728L);                   // 16777216 B  (W bf16, contiguous after xb)
  u16* kvsc = (u16*)(ws + 134217728L + 16777216L);       // 67108864 B  (bf16 C)

  hipLaunchKernelGGL(k_cvt, dim3(36864), dim3(256), 0, stream, x, W_kv, W_gate, xb);
  hipLaunchKernelGGL(k_gemm, dim3(512), dim3(512), 0, stream, xb, wb, kvsc);
  hipLaunchKernelGGL(k_pool, dim3(4096), dim3(256), 0, stream, kvsc, ape, norm_w, freqs, out);
}